// Round 8
// baseline (209.387 us; speedup 1.0000x reference)
//
#include <hip/hip_runtime.h>
#include <math.h>

#define TT 512
#define BB 64
#define II 256
#define HH 512
#define BH (BB*HH)           // 32768
#define TBH ((size_t)TT*BH)  // 16777216
#define MM (TT*BB)           // 32768

typedef float f32x4 __attribute__((ext_vector_type(4)));
typedef _Float16 f16x8 __attribute__((ext_vector_type(8)));
typedef unsigned short u16;

__device__ __forceinline__ void gload16(const void* g, void* l) {
    __builtin_amdgcn_global_load_lds(
        (const __attribute__((address_space(1))) unsigned int*)g,
        (__attribute__((address_space(3))) unsigned int*)l, 16, 0, 0);
}

// ---------------------------------------------------------------------------
// Pack W0,W1 [N][K] f32 -> fragment-major f16 (8 f16 = 16 B per fragment)
// ---------------------------------------------------------------------------
__global__ __launch_bounds__(256)
void pack_w2(const float* __restrict__ W0, const float* __restrict__ W1,
             _Float16* __restrict__ P0, _Float16* __restrict__ P1,
             int nf0, int nf1)
{
    const int i = blockIdx.x * 256 + threadIdx.x;
    const float* src; _Float16* dst;
    if (i < nf0) { src = W0 + (size_t)i * 8;  dst = P0 + (size_t)i * 8; }
    else         { const int j = i - nf0; if (j >= nf1) return;
                   src = W1 + (size_t)j * 8;  dst = P1 + (size_t)j * 8; }
    f16x8 h8;
#pragma unroll
    for (int j = 0; j < 8; ++j) h8[j] = (_Float16)src[j];
    *(f16x8*)dst = h8;
}

// ---------------------------------------------------------------------------
// GEMM variant 1: A f32 (reg-staged + cvt to f16 in LDS, padded rows).
//   C[M][N] = A[M][K] * W_f16[N][K]^T + bias ;  OutT = f16 or f32
// 128x128 tile, BK=32, 4 waves, 4x4 16x16x32 f16 frags.
// ---------------------------------------------------------------------------
template<typename OutT>
__global__ __launch_bounds__(256, 4)
void gemm_f32a(const float* __restrict__ A, const _Float16* __restrict__ Bp,
               const float* __restrict__ bias, OutT* __restrict__ C,
               int M, int N, int K)
{
    const int K8 = K >> 3;
    __shared__ _Float16 As[128][40];   // padded: row stride 80 B

    const int tid  = threadIdx.x;
    const int lane = tid & 63;
    const int wid  = tid >> 6;
    const int wr   = wid >> 1, wc = wid & 1;

    const int nbn = N >> 7;
    const int nt  = (M >> 7) * nbn;
    const int per = nt >> 3;
    const int logical = (blockIdx.x & 7) * per + (blockIdx.x >> 3);
    const int bm = logical / nbn;
    const int bn = logical % nbn;
    const int row0 = bm * 128;
    const int col0 = bn * 128;

    const int s_row = tid >> 1;
    const int s_kh  = (tid & 1) * 16;
    const float* Ap = A + (size_t)(row0 + s_row) * K + s_kh;

    const int fr  = lane & 15;
    const int q   = lane >> 4;
    const int ko8 = q * 8;

    f32x4 acc[4][4];
#pragma unroll
    for (int m = 0; m < 4; ++m)
#pragma unroll
        for (int n = 0; n < 4; ++n)
#pragma unroll
            for (int r = 0; r < 4; ++r) acc[m][n][r] = 0.f;

    const _Float16* bbase[4];
#pragma unroll
    for (int n = 0; n < 4; ++n) {
        const int col = col0 + wc * 64 + n * 16 + fr;
        bbase[n] = Bp + ((size_t)col * K8 + q) * 8;
    }

    f32x4 a_ld[4];
#pragma unroll
    for (int qq = 0; qq < 4; ++qq) a_ld[qq] = *(const f32x4*)(Ap + qq * 4);

    const int nkt = K >> 5;
    for (int kt = 0; kt < nkt; ++kt) {
        __syncthreads();
#pragma unroll
        for (int half = 0; half < 2; ++half) {
            f16x8 h8;
#pragma unroll
            for (int j = 0; j < 8; ++j)
                h8[j] = (_Float16)a_ld[half * 2 + (j >> 2)][j & 3];
            *(f16x8*)&As[s_row][s_kh + half * 8] = h8;
        }
        __syncthreads();

        f16x8 bfr[4];
#pragma unroll
        for (int n = 0; n < 4; ++n)
            bfr[n] = *(const f16x8*)(bbase[n] + (size_t)kt * 32);

        if (kt + 1 < nkt) {
            const float* apn = Ap + (size_t)(kt + 1) * 32;
#pragma unroll
            for (int qq = 0; qq < 4; ++qq) a_ld[qq] = *(const f32x4*)(apn + qq * 4);
        }

#pragma unroll
        for (int m = 0; m < 4; ++m) {
            const int row = wr * 64 + m * 16 + fr;
            f16x8 af = *(const f16x8*)&As[row][ko8];
#pragma unroll
            for (int n = 0; n < 4; ++n)
                acc[m][n] = __builtin_amdgcn_mfma_f32_16x16x32_f16(af, bfr[n], acc[m][n], 0, 0, 0);
        }
    }

#pragma unroll
    for (int n = 0; n < 4; ++n) {
        const int gc = col0 + wc * 64 + n * 16 + fr;
        const float bj = bias[gc];
#pragma unroll
        for (int m = 0; m < 4; ++m) {
            const int gr0 = row0 + wr * 64 + m * 16 + q * 4;
#pragma unroll
            for (int r = 0; r < 4; ++r)
                C[(size_t)(gr0 + r) * N + gc] = (OutT)(acc[m][n][r] + bj);
        }
    }
}

// ---------------------------------------------------------------------------
// GEMM variant 2: A f16 (m97-exact global_load_lds staging, linear 8 KB LDS).
// B fragment regs double-buffered (prefetch kt+1 during MFMA).
// ---------------------------------------------------------------------------
template<typename OutT>
__global__ __launch_bounds__(256, 3)
void gemm_f16a(const _Float16* __restrict__ A, const _Float16* __restrict__ Bp,
               const float* __restrict__ bias, OutT* __restrict__ C,
               int M, int N, int K)
{
    const int K8 = K >> 3;
    __shared__ _Float16 As[128 * 32];   // 8 KB linear (gload_lds dest)

    const int tid  = threadIdx.x;
    const int lane = tid & 63;
    const int wid  = tid >> 6;
    const int wr   = wid >> 1, wc = wid & 1;

    const int nbn = N >> 7;
    const int nt  = (M >> 7) * nbn;
    const int per = nt >> 3;
    const int logical = (blockIdx.x & 7) * per + (blockIdx.x >> 3);
    const int bm = logical / nbn;
    const int bn = logical % nbn;
    const int row0 = bm * 128;
    const int col0 = bn * 128;

    const int a_row = lane >> 2;        // row within 16-row chunk
    const int a_kk  = (lane & 3) * 8;   // f16 offset (16 B granules)

    const int fr  = lane & 15;
    const int q   = lane >> 4;
    const int ko8 = q * 8;

    f32x4 acc[4][4];
#pragma unroll
    for (int m = 0; m < 4; ++m)
#pragma unroll
        for (int n = 0; n < 4; ++n)
#pragma unroll
            for (int r = 0; r < 4; ++r) acc[m][n][r] = 0.f;

    const _Float16* bbase[4];
#pragma unroll
    for (int n = 0; n < 4; ++n) {
        const int col = col0 + wc * 64 + n * 16 + fr;
        bbase[n] = Bp + ((size_t)col * K8 + q) * 8;
    }

    // B prologue (kt=0)
    f16x8 bfr[4], bnf[4];
#pragma unroll
    for (int n = 0; n < 4; ++n) bfr[n] = *(const f16x8*)(bbase[n]);

    const int nkt = K >> 5;
    for (int kt = 0; kt < nkt; ++kt) {
        const int k0 = kt * 32;
        __syncthreads();                 // waves done reading prev tile
#pragma unroll
        for (int i = 0; i < 2; ++i) {
            const int chunk = wid * 2 + i;
            const size_t ga = (size_t)(row0 + chunk * 16 + a_row) * K + k0 + a_kk;
            gload16(A + ga, (char*)&As[0] + chunk * 1024 + (lane & 3) * 16
                               + (size_t)(a_row) * 0);   // dest = chunk*1024 + lane*16
        }
        // NOTE: dest above must be exactly chunk*1024 + lane*16; rewrite plainly:
        __syncthreads();                 // vmcnt drained -> tile ready

        if (kt + 1 < nkt) {              // B prefetch overlaps MFMA
#pragma unroll
            for (int n = 0; n < 4; ++n)
                bnf[n] = *(const f16x8*)(bbase[n] + (size_t)(kt + 1) * 32);
        }

#pragma unroll
        for (int m = 0; m < 4; ++m) {
            const int row = wr * 64 + m * 16 + fr;
            f16x8 af = *(const f16x8*)&As[row * 32 + ko8];
#pragma unroll
            for (int n = 0; n < 4; ++n)
                acc[m][n] = __builtin_amdgcn_mfma_f32_16x16x32_f16(af, bfr[n], acc[m][n], 0, 0, 0);
        }
#pragma unroll
        for (int n = 0; n < 4; ++n) bfr[n] = bnf[n];
    }

#pragma unroll
    for (int n = 0; n < 4; ++n) {
        const int gc = col0 + wc * 64 + n * 16 + fr;
        const float bj = bias[gc];
#pragma unroll
        for (int m = 0; m < 4; ++m) {
            const int gr0 = row0 + wr * 64 + m * 16 + q * 4;
#pragma unroll
            for (int r = 0; r < 4; ++r)
                C[(size_t)(gr0 + r) * N + gc] = (OutT)(acc[m][n][r] + bj);
        }
    }
}

// ---------------------------------------------------------------------------
// Recurrence: one thread per (b,h); 16-step blocks, distance-2 prefetch.
// PreT = f16 (d_ws plan, no aliasing) or f32 (fallback: pre aliases go,
// element-exact read-before-write per thread). EMITF16: also store xo as f16
// (feeds gemm_f16a next layer).
// ---------------------------------------------------------------------------
template<typename PreT, bool EMITF16, bool NTX, bool NTG>
__global__ __launch_bounds__(64)
void skip_indrnn_rec(const PreT* __restrict__ pre, const float* __restrict__ h0,
                     const float* __restrict__ w_hh, const float* __restrict__ w_uh,
                     const float* __restrict__ b_uh, int layer,
                     float* __restrict__ xo, float* __restrict__ go,
                     _Float16* __restrict__ xo16)
{
    const int idx = blockIdx.x * 64 + threadIdx.x;
    const int h = idx & (HH - 1);

    float whh = w_hh[layer * HH + h];
    whh = fminf(fmaxf(whh, -1000.f), 1000.f);
    const float wuh = w_uh[layer * HH + h];
    const float buh = b_uh[layer];

    float hx  = h0[layer * HH + h];
    float up  = 1.f;
    float cum = 0.f;

    const int SB = 16;
    const int NB = TT / SB;              // 32
    float cur[SB], nx1[SB], nx2[SB];
#pragma unroll
    for (int j = 0; j < SB; ++j) cur[j] = (float)pre[(size_t)j * BH + idx];
#pragma unroll
    for (int j = 0; j < SB; ++j) nx1[j] = (float)pre[(size_t)(SB + j) * BH + idx];

    for (int tb = 0; tb < NB; ++tb) {
        if (tb + 2 < NB) {
#pragma unroll
            for (int j = 0; j < SB; ++j)
                nx2[j] = (float)pre[(size_t)((tb + 2) * SB + j) * BH + idx];
        }
#pragma unroll
        for (int j = 0; j < SB; ++j) {
            const int t = tb * SB + j;
            const float nhx   = fmaxf(fmaf(whh, hx, cur[j]), 0.f);
            const float z     = fmaf(nhx, wuh, buh);
            const float tilde = 1.f / (1.f + __expf(-z));
            const float c     = cum + fminf(up, 1.f - cum);
            const float g     = rintf(c);
            const float nh    = (g > 0.5f) ? nhx   : hx;
            const float nup   = (g > 0.5f) ? tilde : up;
            const float ncum  = (g > 0.5f) ? 0.f   : c;
            if (NTX) __builtin_nontemporal_store(nh, &xo[(size_t)t * BH + idx]);
            else     xo[(size_t)t * BH + idx] = nh;
            if (NTG) __builtin_nontemporal_store(g, &go[(size_t)t * BH + idx]);
            else     go[(size_t)t * BH + idx] = g;
            if (EMITF16) {
                const _Float16 hv = (_Float16)nh;
                u16 bits; __builtin_memcpy(&bits, &hv, 2);
                __builtin_nontemporal_store(bits, (u16*)&xo16[(size_t)t * BH + idx]);
            }
            hx = nh; up = nup; cum = ncum;
        }
#pragma unroll
        for (int j = 0; j < SB; ++j) { cur[j] = nx1[j]; nx1[j] = nx2[j]; }
    }
}

// ---------------------------------------------------------------------------
// d_ws plan (ws >= 100 MiB; fills show ws = 1 GiB):
//   P0 @0 (256 KB), P1 @256 KB (512 KB), pre0 @1 MiB (32 MiB),
//   pre1 @33 MiB, xo0_f16 @65 MiB. End ~97 MiB. d_out = pure outputs.
// Fallback (small ws): round-6 proven plan — packed W in X1, f32 pre in G1
// (element-exact per-thread alias), GEMM1 reg-staged on X0 f32.
// ---------------------------------------------------------------------------
extern "C" void kernel_launch(void* const* d_in, const int* in_sizes, int n_in,
                              void* d_out, int out_size, void* d_ws, size_t ws_size,
                              hipStream_t stream) {
    const float* x    = (const float*)d_in[0];
    const float* h0   = (const float*)d_in[1];
    const float* W0   = (const float*)d_in[2];
    const float* W1   = (const float*)d_in[3];
    const float* b_ih = (const float*)d_in[4];
    const float* w_hh = (const float*)d_in[5];
    const float* w_uh = (const float*)d_in[6];
    const float* b_uh = (const float*)d_in[7];

    float* out = (float*)d_out;
    float* X0 = out;
    float* X1 = out + TBH;
    float* G0 = out + 2 * TBH;
    float* G1 = out + 3 * TBH;

    const int nf0 = HH * II / 8;          // 16384
    const int nf1 = HH * HH / 8;          // 32768

    if (ws_size >= (size_t)100 * 1024 * 1024) {
        char* ws = (char*)d_ws;
        _Float16* P0    = (_Float16*)ws;
        _Float16* P1    = (_Float16*)(ws + (size_t)256 * 1024);
        _Float16* pre0  = (_Float16*)(ws + (size_t)1 * 1024 * 1024);
        _Float16* pre1  = (_Float16*)(ws + (size_t)33 * 1024 * 1024);
        _Float16* xo0h  = (_Float16*)(ws + (size_t)65 * 1024 * 1024);

        pack_w2<<<(nf0 + nf1 + 255) / 256, 256, 0, stream>>>(W0, W1, P0, P1, nf0, nf1);

        gemm_f32a<_Float16><<<1024, 256, 0, stream>>>(x, P0, b_ih, pre0, MM, HH, II);
        skip_indrnn_rec<_Float16, true, false, true><<<BH / 64, 64, 0, stream>>>(
            pre0, h0, w_hh, w_uh, b_uh, 0, X0, G0, xo0h);
        gemm_f16a<_Float16><<<1024, 256, 0, stream>>>(xo0h, P1, b_ih + HH, pre1, MM, HH, HH);
        skip_indrnn_rec<_Float16, false, true, true><<<BH / 64, 64, 0, stream>>>(
            pre1, h0, w_hh, w_uh, b_uh, 1, X1, G1, nullptr);
    } else {
        _Float16* P0 = (_Float16*)X1;
        _Float16* P1 = P0 + (size_t)nf0 * 8;
        float* pre = G1;

        pack_w2<<<(nf0 + nf1 + 255) / 256, 256, 0, stream>>>(W0, W1, P0, P1, nf0, nf1);

        gemm_f32a<float><<<1024, 256, 0, stream>>>(x, P0, b_ih, pre, MM, HH, II);
        skip_indrnn_rec<float, false, false, true><<<BH / 64, 64, 0, stream>>>(
            pre, h0, w_hh, w_uh, b_uh, 0, X0, G0, nullptr);
        gemm_f32a<float><<<1024, 256, 0, stream>>>(X0, P1, b_ih + HH, pre, MM, HH, HH);
        skip_indrnn_rec<float, false, true, true><<<BH / 64, 64, 0, stream>>>(
            pre, h0, w_hh, w_uh, b_uh, 1, X1, G1, nullptr);
    }
}

// Round 9
// 208.659 us; speedup vs baseline: 1.0035x; 1.0035x over previous
//
#include <hip/hip_runtime.h>
#include <math.h>

#define TT 512
#define BB 64
#define II 256
#define HH 512
#define BH (BB*HH)           // 32768
#define TBH ((size_t)TT*BH)  // 16777216
#define MM (TT*BB)           // 32768

typedef float f32x4 __attribute__((ext_vector_type(4)));
typedef _Float16 f16x8 __attribute__((ext_vector_type(8)));
typedef unsigned short u16;

// ---------------------------------------------------------------------------
// Pack W0,W1 [N][K] f32 -> fragment-major f16 (8 f16 = 16 B per fragment)
// ---------------------------------------------------------------------------
__global__ __launch_bounds__(256)
void pack_w2(const float* __restrict__ W0, const float* __restrict__ W1,
             _Float16* __restrict__ P0, _Float16* __restrict__ P1,
             int nf0, int nf1)
{
    const int i = blockIdx.x * 256 + threadIdx.x;
    const float* src; _Float16* dst;
    if (i < nf0) { src = W0 + (size_t)i * 8;  dst = P0 + (size_t)i * 8; }
    else         { const int j = i - nf0; if (j >= nf1) return;
                   src = W1 + (size_t)j * 8;  dst = P1 + (size_t)j * 8; }
    f16x8 h8;
#pragma unroll
    for (int j = 0; j < 8; ++j) h8[j] = (_Float16)src[j];
    *(f16x8*)dst = h8;
}

// ---------------------------------------------------------------------------
// GEMM, A = f32 (reg-staged, cvt f16 during LDS stage; round-7 proven).
//   C[M][N] = A[M][K] * W_f16[N][K]^T + bias ; OutT = f16 (pre) or f32
// 128x128 tile, BK=32, 4 waves (2x2), 4x4 16x16x32 f16 frags.
// A-prefetch for kt+1 issued before the MFMA block (latency overlapped).
// Tile order: bn-major + XCD-clustered.
// ---------------------------------------------------------------------------
template<typename OutT>
__global__ __launch_bounds__(256, 4)
void gemm_f32a(const float* __restrict__ A, const _Float16* __restrict__ Bp,
               const float* __restrict__ bias, OutT* __restrict__ C,
               int M, int N, int K)
{
    const int K8 = K >> 3;
    __shared__ _Float16 As[128][40];   // padded: row stride 80 B

    const int tid  = threadIdx.x;
    const int lane = tid & 63;
    const int wid  = tid >> 6;
    const int wr   = wid >> 1, wc = wid & 1;

    const int nbn = N >> 7;
    const int nt  = (M >> 7) * nbn;
    const int per = nt >> 3;
    const int logical = (blockIdx.x & 7) * per + (blockIdx.x >> 3);
    const int bm = logical / nbn;
    const int bn = logical % nbn;
    const int row0 = bm * 128;
    const int col0 = bn * 128;

    const int s_row = tid >> 1;
    const int s_kh  = (tid & 1) * 16;
    const float* Ap = A + (size_t)(row0 + s_row) * K + s_kh;

    const int fr  = lane & 15;
    const int q   = lane >> 4;
    const int ko8 = q * 8;

    f32x4 acc[4][4];
#pragma unroll
    for (int m = 0; m < 4; ++m)
#pragma unroll
        for (int n = 0; n < 4; ++n)
#pragma unroll
            for (int r = 0; r < 4; ++r) acc[m][n][r] = 0.f;

    const _Float16* bbase[4];
#pragma unroll
    for (int n = 0; n < 4; ++n) {
        const int col = col0 + wc * 64 + n * 16 + fr;
        bbase[n] = Bp + ((size_t)col * K8 + q) * 8;
    }

    f32x4 a_ld[4];
#pragma unroll
    for (int qq = 0; qq < 4; ++qq) a_ld[qq] = *(const f32x4*)(Ap + qq * 4);

    const int nkt = K >> 5;
    for (int kt = 0; kt < nkt; ++kt) {
        __syncthreads();
#pragma unroll
        for (int half = 0; half < 2; ++half) {
            f16x8 h8;
#pragma unroll
            for (int j = 0; j < 8; ++j)
                h8[j] = (_Float16)a_ld[half * 2 + (j >> 2)][j & 3];
            *(f16x8*)&As[s_row][s_kh + half * 8] = h8;
        }
        __syncthreads();

        f16x8 bfr[4];
#pragma unroll
        for (int n = 0; n < 4; ++n)
            bfr[n] = *(const f16x8*)(bbase[n] + (size_t)kt * 32);

        if (kt + 1 < nkt) {
            const float* apn = Ap + (size_t)(kt + 1) * 32;
#pragma unroll
            for (int qq = 0; qq < 4; ++qq) a_ld[qq] = *(const f32x4*)(apn + qq * 4);
        }

#pragma unroll
        for (int m = 0; m < 4; ++m) {
            const int row = wr * 64 + m * 16 + fr;
            f16x8 af = *(const f16x8*)&As[row][ko8];
#pragma unroll
            for (int n = 0; n < 4; ++n)
                acc[m][n] = __builtin_amdgcn_mfma_f32_16x16x32_f16(af, bfr[n], acc[m][n], 0, 0, 0);
        }
    }

#pragma unroll
    for (int n = 0; n < 4; ++n) {
        const int gc = col0 + wc * 64 + n * 16 + fr;
        const float bj = bias[gc];
#pragma unroll
        for (int m = 0; m < 4; ++m) {
            const int gr0 = row0 + wr * 64 + m * 16 + q * 4;
#pragma unroll
            for (int r = 0; r < 4; ++r)
                C[(size_t)(gr0 + r) * N + gc] = (OutT)(acc[m][n][r] + bj);
        }
    }
}

// ---------------------------------------------------------------------------
// GEMM, A = f16 (reg-staged: 2x16B loads/thread/K-step, no cvt, straight
// copy to padded LDS; same overlapped-prefetch structure as gemm_f32a).
// ---------------------------------------------------------------------------
template<typename OutT>
__global__ __launch_bounds__(256, 4)
void gemm_f16a_reg(const _Float16* __restrict__ A, const _Float16* __restrict__ Bp,
                   const float* __restrict__ bias, OutT* __restrict__ C,
                   int M, int N, int K)
{
    const int K8 = K >> 3;
    __shared__ _Float16 As[128][40];

    const int tid  = threadIdx.x;
    const int lane = tid & 63;
    const int wid  = tid >> 6;
    const int wr   = wid >> 1, wc = wid & 1;

    const int nbn = N >> 7;
    const int nt  = (M >> 7) * nbn;
    const int per = nt >> 3;
    const int logical = (blockIdx.x & 7) * per + (blockIdx.x >> 3);
    const int bm = logical / nbn;
    const int bn = logical % nbn;
    const int row0 = bm * 128;
    const int col0 = bn * 128;

    const int s_row = tid >> 1;
    const int s_kh  = (tid & 1) * 16;
    const _Float16* Ap = A + (size_t)(row0 + s_row) * K + s_kh;

    const int fr  = lane & 15;
    const int q   = lane >> 4;
    const int ko8 = q * 8;

    f32x4 acc[4][4];
#pragma unroll
    for (int m = 0; m < 4; ++m)
#pragma unroll
        for (int n = 0; n < 4; ++n)
#pragma unroll
            for (int r = 0; r < 4; ++r) acc[m][n][r] = 0.f;

    const _Float16* bbase[4];
#pragma unroll
    for (int n = 0; n < 4; ++n) {
        const int col = col0 + wc * 64 + n * 16 + fr;
        bbase[n] = Bp + ((size_t)col * K8 + q) * 8;
    }

    f16x8 a_ld[2];
#pragma unroll
    for (int hh = 0; hh < 2; ++hh) a_ld[hh] = *(const f16x8*)(Ap + hh * 8);

    const int nkt = K >> 5;
    for (int kt = 0; kt < nkt; ++kt) {
        __syncthreads();
#pragma unroll
        for (int hh = 0; hh < 2; ++hh)
            *(f16x8*)&As[s_row][s_kh + hh * 8] = a_ld[hh];
        __syncthreads();

        f16x8 bfr[4];
#pragma unroll
        for (int n = 0; n < 4; ++n)
            bfr[n] = *(const f16x8*)(bbase[n] + (size_t)kt * 32);

        if (kt + 1 < nkt) {
            const _Float16* apn = Ap + (size_t)(kt + 1) * 32;
#pragma unroll
            for (int hh = 0; hh < 2; ++hh) a_ld[hh] = *(const f16x8*)(apn + hh * 8);
        }

#pragma unroll
        for (int m = 0; m < 4; ++m) {
            const int row = wr * 64 + m * 16 + fr;
            f16x8 af = *(const f16x8*)&As[row][ko8];
#pragma unroll
            for (int n = 0; n < 4; ++n)
                acc[m][n] = __builtin_amdgcn_mfma_f32_16x16x32_f16(af, bfr[n], acc[m][n], 0, 0, 0);
        }
    }

#pragma unroll
    for (int n = 0; n < 4; ++n) {
        const int gc = col0 + wc * 64 + n * 16 + fr;
        const float bj = bias[gc];
#pragma unroll
        for (int m = 0; m < 4; ++m) {
            const int gr0 = row0 + wr * 64 + m * 16 + q * 4;
#pragma unroll
            for (int r = 0; r < 4; ++r)
                C[(size_t)(gr0 + r) * N + gc] = (OutT)(acc[m][n][r] + bj);
        }
    }
}

// ---------------------------------------------------------------------------
// Recurrence: one thread per (b,h); 16-step blocks, DISTANCE-3 prefetch
// (48 loads in flight — restores in-flight bytes after f16 halving).
// EMITF16: also store xo as f16 (regular store -> L3-resident for GEMM1).
// In the fallback (PreT=f32) pre aliases go: element t read (prefetch,
// iter tb-3) strictly before written (iter tb), same thread.
// ---------------------------------------------------------------------------
template<typename PreT, bool EMITF16, bool NTX, bool NTG>
__global__ __launch_bounds__(64)
void skip_indrnn_rec(const PreT* __restrict__ pre, const float* __restrict__ h0,
                     const float* __restrict__ w_hh, const float* __restrict__ w_uh,
                     const float* __restrict__ b_uh, int layer,
                     float* __restrict__ xo, float* __restrict__ go,
                     _Float16* __restrict__ xo16)
{
    const int idx = blockIdx.x * 64 + threadIdx.x;
    const int h = idx & (HH - 1);

    float whh = w_hh[layer * HH + h];
    whh = fminf(fmaxf(whh, -1000.f), 1000.f);
    const float wuh = w_uh[layer * HH + h];
    const float buh = b_uh[layer];

    float hx  = h0[layer * HH + h];
    float up  = 1.f;
    float cum = 0.f;

    const int SB = 16;
    const int NB = TT / SB;              // 32
    float cur[SB], nx1[SB], nx2[SB], nx3[SB];
#pragma unroll
    for (int j = 0; j < SB; ++j) cur[j] = (float)pre[(size_t)j * BH + idx];
#pragma unroll
    for (int j = 0; j < SB; ++j) nx1[j] = (float)pre[(size_t)(SB + j) * BH + idx];
#pragma unroll
    for (int j = 0; j < SB; ++j) nx2[j] = (float)pre[(size_t)(2 * SB + j) * BH + idx];

    for (int tb = 0; tb < NB; ++tb) {
        if (tb + 3 < NB) {
#pragma unroll
            for (int j = 0; j < SB; ++j)
                nx3[j] = (float)pre[(size_t)((tb + 3) * SB + j) * BH + idx];
        }
#pragma unroll
        for (int j = 0; j < SB; ++j) {
            const int t = tb * SB + j;
            const float nhx   = fmaxf(fmaf(whh, hx, cur[j]), 0.f);
            const float z     = fmaf(nhx, wuh, buh);
            const float tilde = 1.f / (1.f + __expf(-z));
            const float c     = cum + fminf(up, 1.f - cum);
            const float g     = rintf(c);
            const float nh    = (g > 0.5f) ? nhx   : hx;
            const float nup   = (g > 0.5f) ? tilde : up;
            const float ncum  = (g > 0.5f) ? 0.f   : c;
            if (NTX) __builtin_nontemporal_store(nh, &xo[(size_t)t * BH + idx]);
            else     xo[(size_t)t * BH + idx] = nh;
            if (NTG) __builtin_nontemporal_store(g, &go[(size_t)t * BH + idx]);
            else     go[(size_t)t * BH + idx] = g;
            if (EMITF16)
                xo16[(size_t)t * BH + idx] = (_Float16)nh;   // regular: keep in L3
            hx = nh; up = nup; cum = ncum;
        }
#pragma unroll
        for (int j = 0; j < SB; ++j) { cur[j] = nx1[j]; nx1[j] = nx2[j]; nx2[j] = nx3[j]; }
    }
}

// ---------------------------------------------------------------------------
// d_ws plan (ws = 1 GiB per observed fills; need ~97 MiB):
//   P0 @0 (256 KB), P1 @256 KB (512 KB), pre0 f16 @1 MiB (32 MiB),
//   pre1 f16 @33 MiB (32 MiB), xo0h f16 @65 MiB (32 MiB).
// d_out = pure outputs. Fallback (small ws) = round-7 in-d_out plan, all f32.
// ---------------------------------------------------------------------------
extern "C" void kernel_launch(void* const* d_in, const int* in_sizes, int n_in,
                              void* d_out, int out_size, void* d_ws, size_t ws_size,
                              hipStream_t stream) {
    const float* x    = (const float*)d_in[0];
    const float* h0   = (const float*)d_in[1];
    const float* W0   = (const float*)d_in[2];
    const float* W1   = (const float*)d_in[3];
    const float* b_ih = (const float*)d_in[4];
    const float* w_hh = (const float*)d_in[5];
    const float* w_uh = (const float*)d_in[6];
    const float* b_uh = (const float*)d_in[7];

    float* out = (float*)d_out;
    float* X0 = out;
    float* X1 = out + TBH;
    float* G0 = out + 2 * TBH;
    float* G1 = out + 3 * TBH;

    const int nf0 = HH * II / 8;          // 16384
    const int nf1 = HH * HH / 8;          // 32768

    if (ws_size >= (size_t)100 * 1024 * 1024) {
        char* ws = (char*)d_ws;
        _Float16* P0   = (_Float16*)ws;
        _Float16* P1   = (_Float16*)(ws + (size_t)256 * 1024);
        _Float16* pre0 = (_Float16*)(ws + (size_t)1  * 1024 * 1024);
        _Float16* pre1 = (_Float16*)(ws + (size_t)33 * 1024 * 1024);
        _Float16* xo0h = (_Float16*)(ws + (size_t)65 * 1024 * 1024);

        pack_w2<<<(nf0 + nf1 + 255) / 256, 256, 0, stream>>>(W0, W1, P0, P1, nf0, nf1);

        gemm_f32a<_Float16><<<1024, 256, 0, stream>>>(x, P0, b_ih, pre0, MM, HH, II);
        skip_indrnn_rec<_Float16, true, true, true><<<BH / 64, 64, 0, stream>>>(
            pre0, h0, w_hh, w_uh, b_uh, 0, X0, G0, xo0h);
        gemm_f16a_reg<_Float16><<<1024, 256, 0, stream>>>(xo0h, P1, b_ih + HH, pre1, MM, HH, HH);
        skip_indrnn_rec<_Float16, false, true, true><<<BH / 64, 64, 0, stream>>>(
            pre1, h0, w_hh, w_uh, b_uh, 1, X1, G1, nullptr);
    } else {
        _Float16* P0 = (_Float16*)X1;
        _Float16* P1 = P0 + (size_t)nf0 * 8;
        float* pre = G1;

        pack_w2<<<(nf0 + nf1 + 255) / 256, 256, 0, stream>>>(W0, W1, P0, P1, nf0, nf1);

        gemm_f32a<float><<<1024, 256, 0, stream>>>(x, P0, b_ih, pre, MM, HH, II);
        skip_indrnn_rec<float, false, false, true><<<BH / 64, 64, 0, stream>>>(
            pre, h0, w_hh, w_uh, b_uh, 0, X0, G0, nullptr);
        gemm_f32a<float><<<1024, 256, 0, stream>>>(X0, P1, b_ih + HH, pre, MM, HH, HH);
        skip_indrnn_rec<float, false, true, true><<<BH / 64, 64, 0, stream>>>(
            pre, h0, w_hh, w_uh, b_uh, 1, X1, G1, nullptr);
    }
}

// Round 10
// 194.363 us; speedup vs baseline: 1.0773x; 1.0736x over previous
//
#include <hip/hip_runtime.h>
#include <math.h>

#define TT 512
#define BB 64
#define II 256
#define HH 512
#define BH (BB*HH)           // 32768
#define TBH ((size_t)TT*BH)  // 16777216
#define MM (TT*BB)           // 32768

typedef float f32x4 __attribute__((ext_vector_type(4)));
typedef _Float16 f16x8 __attribute__((ext_vector_type(8)));
typedef unsigned short u16;

// ---------------------------------------------------------------------------
// Pack W0,W1 [N][K] f32 -> fragment-major f16 (8 f16 = 16 B per fragment)
// ---------------------------------------------------------------------------
__global__ __launch_bounds__(256)
void pack_w2(const float* __restrict__ W0, const float* __restrict__ W1,
             _Float16* __restrict__ P0, _Float16* __restrict__ P1,
             int nf0, int nf1)
{
    const int i = blockIdx.x * 256 + threadIdx.x;
    const float* src; _Float16* dst;
    if (i < nf0) { src = W0 + (size_t)i * 8;  dst = P0 + (size_t)i * 8; }
    else         { const int j = i - nf0; if (j >= nf1) return;
                   src = W1 + (size_t)j * 8;  dst = P1 + (size_t)j * 8; }
    f16x8 h8;
#pragma unroll
    for (int j = 0; j < 8; ++j) h8[j] = (_Float16)src[j];
    *(f16x8*)dst = h8;
}

// ---------------------------------------------------------------------------
// GEMM, A = f32 (reg-staged, cvt f16 during LDS stage; round-7 proven).
//   C[M][N] = A[M][K] * W_f16[N][K]^T + bias ; OutT = f16 (pre) or f32
// 128x128 tile, BK=32, 4 waves (2x2), 4x4 16x16x32 f16 frags.
// ---------------------------------------------------------------------------
template<typename OutT>
__global__ __launch_bounds__(256, 4)
void gemm_f32a(const float* __restrict__ A, const _Float16* __restrict__ Bp,
               const float* __restrict__ bias, OutT* __restrict__ C,
               int M, int N, int K)
{
    const int K8 = K >> 3;
    __shared__ _Float16 As[128][40];   // padded: row stride 80 B

    const int tid  = threadIdx.x;
    const int lane = tid & 63;
    const int wid  = tid >> 6;
    const int wr   = wid >> 1, wc = wid & 1;

    const int nbn = N >> 7;
    const int nt  = (M >> 7) * nbn;
    const int per = nt >> 3;
    const int logical = (blockIdx.x & 7) * per + (blockIdx.x >> 3);
    const int bm = logical / nbn;
    const int bn = logical % nbn;
    const int row0 = bm * 128;
    const int col0 = bn * 128;

    const int s_row = tid >> 1;
    const int s_kh  = (tid & 1) * 16;
    const float* Ap = A + (size_t)(row0 + s_row) * K + s_kh;

    const int fr  = lane & 15;
    const int q   = lane >> 4;
    const int ko8 = q * 8;

    f32x4 acc[4][4];
#pragma unroll
    for (int m = 0; m < 4; ++m)
#pragma unroll
        for (int n = 0; n < 4; ++n)
#pragma unroll
            for (int r = 0; r < 4; ++r) acc[m][n][r] = 0.f;

    const _Float16* bbase[4];
#pragma unroll
    for (int n = 0; n < 4; ++n) {
        const int col = col0 + wc * 64 + n * 16 + fr;
        bbase[n] = Bp + ((size_t)col * K8 + q) * 8;
    }

    f32x4 a_ld[4];
#pragma unroll
    for (int qq = 0; qq < 4; ++qq) a_ld[qq] = *(const f32x4*)(Ap + qq * 4);

    const int nkt = K >> 5;
    for (int kt = 0; kt < nkt; ++kt) {
        __syncthreads();
#pragma unroll
        for (int half = 0; half < 2; ++half) {
            f16x8 h8;
#pragma unroll
            for (int j = 0; j < 8; ++j)
                h8[j] = (_Float16)a_ld[half * 2 + (j >> 2)][j & 3];
            *(f16x8*)&As[s_row][s_kh + half * 8] = h8;
        }
        __syncthreads();

        f16x8 bfr[4];
#pragma unroll
        for (int n = 0; n < 4; ++n)
            bfr[n] = *(const f16x8*)(bbase[n] + (size_t)kt * 32);

        if (kt + 1 < nkt) {
            const float* apn = Ap + (size_t)(kt + 1) * 32;
#pragma unroll
            for (int qq = 0; qq < 4; ++qq) a_ld[qq] = *(const f32x4*)(apn + qq * 4);
        }

#pragma unroll
        for (int m = 0; m < 4; ++m) {
            const int row = wr * 64 + m * 16 + fr;
            f16x8 af = *(const f16x8*)&As[row][ko8];
#pragma unroll
            for (int n = 0; n < 4; ++n)
                acc[m][n] = __builtin_amdgcn_mfma_f32_16x16x32_f16(af, bfr[n], acc[m][n], 0, 0, 0);
        }
    }

#pragma unroll
    for (int n = 0; n < 4; ++n) {
        const int gc = col0 + wc * 64 + n * 16 + fr;
        const float bj = bias[gc];
#pragma unroll
        for (int m = 0; m < 4; ++m) {
            const int gr0 = row0 + wr * 64 + m * 16 + q * 4;
#pragma unroll
            for (int r = 0; r < 4; ++r)
                C[(size_t)(gr0 + r) * N + gc] = (OutT)(acc[m][n][r] + bj);
        }
    }
}

// ---------------------------------------------------------------------------
// GEMM, A = f16 (reg-staged: 2x16B loads/thread/K-step, no cvt).
// ---------------------------------------------------------------------------
template<typename OutT>
__global__ __launch_bounds__(256, 4)
void gemm_f16a_reg(const _Float16* __restrict__ A, const _Float16* __restrict__ Bp,
                   const float* __restrict__ bias, OutT* __restrict__ C,
                   int M, int N, int K)
{
    const int K8 = K >> 3;
    __shared__ _Float16 As[128][40];

    const int tid  = threadIdx.x;
    const int lane = tid & 63;
    const int wid  = tid >> 6;
    const int wr   = wid >> 1, wc = wid & 1;

    const int nbn = N >> 7;
    const int nt  = (M >> 7) * nbn;
    const int per = nt >> 3;
    const int logical = (blockIdx.x & 7) * per + (blockIdx.x >> 3);
    const int bm = logical / nbn;
    const int bn = logical % nbn;
    const int row0 = bm * 128;
    const int col0 = bn * 128;

    const int s_row = tid >> 1;
    const int s_kh  = (tid & 1) * 16;
    const _Float16* Ap = A + (size_t)(row0 + s_row) * K + s_kh;

    const int fr  = lane & 15;
    const int q   = lane >> 4;
    const int ko8 = q * 8;

    f32x4 acc[4][4];
#pragma unroll
    for (int m = 0; m < 4; ++m)
#pragma unroll
        for (int n = 0; n < 4; ++n)
#pragma unroll
            for (int r = 0; r < 4; ++r) acc[m][n][r] = 0.f;

    const _Float16* bbase[4];
#pragma unroll
    for (int n = 0; n < 4; ++n) {
        const int col = col0 + wc * 64 + n * 16 + fr;
        bbase[n] = Bp + ((size_t)col * K8 + q) * 8;
    }

    f16x8 a_ld[2];
#pragma unroll
    for (int hh = 0; hh < 2; ++hh) a_ld[hh] = *(const f16x8*)(Ap + hh * 8);

    const int nkt = K >> 5;
    for (int kt = 0; kt < nkt; ++kt) {
        __syncthreads();
#pragma unroll
        for (int hh = 0; hh < 2; ++hh)
            *(f16x8*)&As[s_row][s_kh + hh * 8] = a_ld[hh];
        __syncthreads();

        f16x8 bfr[4];
#pragma unroll
        for (int n = 0; n < 4; ++n)
            bfr[n] = *(const f16x8*)(bbase[n] + (size_t)kt * 32);

        if (kt + 1 < nkt) {
            const _Float16* apn = Ap + (size_t)(kt + 1) * 32;
#pragma unroll
            for (int hh = 0; hh < 2; ++hh) a_ld[hh] = *(const f16x8*)(apn + hh * 8);
        }

#pragma unroll
        for (int m = 0; m < 4; ++m) {
            const int row = wr * 64 + m * 16 + fr;
            f16x8 af = *(const f16x8*)&As[row][ko8];
#pragma unroll
            for (int n = 0; n < 4; ++n)
                acc[m][n] = __builtin_amdgcn_mfma_f32_16x16x32_f16(af, bfr[n], acc[m][n], 0, 0, 0);
        }
    }

#pragma unroll
    for (int n = 0; n < 4; ++n) {
        const int gc = col0 + wc * 64 + n * 16 + fr;
        const float bj = bias[gc];
#pragma unroll
        for (int m = 0; m < 4; ++m) {
            const int gr0 = row0 + wr * 64 + m * 16 + q * 4;
#pragma unroll
            for (int r = 0; r < 4; ++r)
                C[(size_t)(gr0 + r) * N + gc] = (OutT)(acc[m][n][r] + bj);
        }
    }
}

// ---------------------------------------------------------------------------
// Recurrence: one thread per (b,h); 16-step blocks; MANUAL 4-deep pipeline
// with named buffers b0..b3 (no rotation moves, no cvt on the load path:
// buffers hold the storage type, cvt at use). Each buffer's loads issue
// >= 3 compute-blocks (~1500 cy) before first use -> HBM latency hidden.
// Fallback (PreT=f32): pre aliases go; reads of block tb happen >= 3 blocks
// before writes to block tb (same thread, program order).
// ---------------------------------------------------------------------------
template<typename PreT, bool EMITF16, bool NTX, bool NTG>
__global__ __launch_bounds__(64)
void skip_indrnn_rec(const PreT* __restrict__ pre, const float* __restrict__ h0,
                     const float* __restrict__ w_hh, const float* __restrict__ w_uh,
                     const float* __restrict__ b_uh, int layer,
                     float* __restrict__ xo, float* __restrict__ go,
                     _Float16* __restrict__ xo16)
{
    const int idx = blockIdx.x * 64 + threadIdx.x;
    const int h = idx & (HH - 1);

    float whh = w_hh[layer * HH + h];
    whh = fminf(fmaxf(whh, -1000.f), 1000.f);
    const float wuh = w_uh[layer * HH + h];
    const float buh = b_uh[layer];

    float hx  = h0[layer * HH + h];
    float up  = 1.f;
    float cum = 0.f;

    const int SB = 16;
    const int NB = TT / SB;              // 32 blocks, stepped 4 at a time

    PreT b0[SB], b1[SB], b2[SB], b3[SB];

#define LOADB(buf, blk)                                                   \
    {   const int _b = (blk);                                             \
        _Pragma("unroll")                                                 \
        for (int j = 0; j < SB; ++j)                                      \
            buf[j] = pre[(size_t)(_b * SB + j) * BH + idx];               \
    }

#define COMPUTEB(buf, blk)                                                \
    {   const int _t0 = (blk) * SB;                                       \
        _Pragma("unroll")                                                 \
        for (int j = 0; j < SB; ++j) {                                    \
            const int t = _t0 + j;                                        \
            const float pv    = (float)buf[j];                            \
            const float nhx   = fmaxf(fmaf(whh, hx, pv), 0.f);            \
            const float z     = fmaf(nhx, wuh, buh);                      \
            const float tilde = 1.f / (1.f + __expf(-z));                 \
            const float c     = cum + fminf(up, 1.f - cum);               \
            const float g     = rintf(c);                                 \
            const float nh    = (g > 0.5f) ? nhx   : hx;                  \
            const float nup   = (g > 0.5f) ? tilde : up;                  \
            const float ncum  = (g > 0.5f) ? 0.f   : c;                   \
            if (NTX) __builtin_nontemporal_store(nh, &xo[(size_t)t * BH + idx]); \
            else     xo[(size_t)t * BH + idx] = nh;                       \
            if (NTG) __builtin_nontemporal_store(g, &go[(size_t)t * BH + idx]);  \
            else     go[(size_t)t * BH + idx] = g;                        \
            if (EMITF16) xo16[(size_t)t * BH + idx] = (_Float16)nh;       \
            hx = nh; up = nup; cum = ncum;                                \
        }                                                                 \
    }

    LOADB(b0, 0);
    LOADB(b1, 1);
    LOADB(b2, 2);

    for (int tb = 0; tb < NB; tb += 4) {
        if (tb + 3 < NB) LOADB(b3, tb + 3);
        COMPUTEB(b0, tb);
        if (tb + 4 < NB) LOADB(b0, tb + 4);
        COMPUTEB(b1, tb + 1);
        if (tb + 5 < NB) LOADB(b1, tb + 5);
        COMPUTEB(b2, tb + 2);
        if (tb + 6 < NB) LOADB(b2, tb + 6);
        COMPUTEB(b3, tb + 3);
    }
#undef LOADB
#undef COMPUTEB
}

// ---------------------------------------------------------------------------
// d_ws plan (ws = 1 GiB per observed fills; need ~97 MiB):
//   P0 @0, P1 @256 KB, pre0 f16 @1 MiB, pre1 f16 @33 MiB, xo0h f16 @65 MiB.
// d_out = pure outputs. Fallback (small ws) = round-7 in-d_out plan, all f32.
// ---------------------------------------------------------------------------
extern "C" void kernel_launch(void* const* d_in, const int* in_sizes, int n_in,
                              void* d_out, int out_size, void* d_ws, size_t ws_size,
                              hipStream_t stream) {
    const float* x    = (const float*)d_in[0];
    const float* h0   = (const float*)d_in[1];
    const float* W0   = (const float*)d_in[2];
    const float* W1   = (const float*)d_in[3];
    const float* b_ih = (const float*)d_in[4];
    const float* w_hh = (const float*)d_in[5];
    const float* w_uh = (const float*)d_in[6];
    const float* b_uh = (const float*)d_in[7];

    float* out = (float*)d_out;
    float* X0 = out;
    float* X1 = out + TBH;
    float* G0 = out + 2 * TBH;
    float* G1 = out + 3 * TBH;

    const int nf0 = HH * II / 8;          // 16384
    const int nf1 = HH * HH / 8;          // 32768

    if (ws_size >= (size_t)100 * 1024 * 1024) {
        char* ws = (char*)d_ws;
        _Float16* P0   = (_Float16*)ws;
        _Float16* P1   = (_Float16*)(ws + (size_t)256 * 1024);
        _Float16* pre0 = (_Float16*)(ws + (size_t)1  * 1024 * 1024);
        _Float16* pre1 = (_Float16*)(ws + (size_t)33 * 1024 * 1024);
        _Float16* xo0h = (_Float16*)(ws + (size_t)65 * 1024 * 1024);

        pack_w2<<<(nf0 + nf1 + 255) / 256, 256, 0, stream>>>(W0, W1, P0, P1, nf0, nf1);

        gemm_f32a<_Float16><<<1024, 256, 0, stream>>>(x, P0, b_ih, pre0, MM, HH, II);
        skip_indrnn_rec<_Float16, true, true, true><<<BH / 64, 64, 0, stream>>>(
            pre0, h0, w_hh, w_uh, b_uh, 0, X0, G0, xo0h);
        gemm_f16a_reg<_Float16><<<1024, 256, 0, stream>>>(xo0h, P1, b_ih + HH, pre1, MM, HH, HH);
        skip_indrnn_rec<_Float16, false, true, true><<<BH / 64, 64, 0, stream>>>(
            pre1, h0, w_hh, w_uh, b_uh, 1, X1, G1, nullptr);
    } else {
        _Float16* P0 = (_Float16*)X1;
        _Float16* P1 = P0 + (size_t)nf0 * 8;
        float* pre = G1;

        pack_w2<<<(nf0 + nf1 + 255) / 256, 256, 0, stream>>>(W0, W1, P0, P1, nf0, nf1);

        gemm_f32a<float><<<1024, 256, 0, stream>>>(x, P0, b_ih, pre, MM, HH, II);
        skip_indrnn_rec<float, false, false, true><<<BH / 64, 64, 0, stream>>>(
            pre, h0, w_hh, w_uh, b_uh, 0, X0, G0, nullptr);
        gemm_f32a<float><<<1024, 256, 0, stream>>>(X0, P1, b_ih + HH, pre, MM, HH, HH);
        skip_indrnn_rec<float, false, true, true><<<BH / 64, 64, 0, stream>>>(
            pre, h0, w_hh, w_uh, b_uh, 1, X1, G1, nullptr);
    }
}